// Round 1
// baseline (428.469 us; speedup 1.0000x reference)
//
#include <hip/hip_runtime.h>
#include <math.h>

#define SS 1024
#define NC 8
#define BWD 170
#define THRESH 1e-4f

typedef unsigned long long ull;

__device__ __forceinline__ float2 cmul(float2 a, float2 b) {
    return make_float2(a.x * b.x - a.y * b.y, a.x * b.y + a.y * b.x);
}

// ---------------------------------------------------------------------------
// Blur + alpha blend + pack two real images into one complex plane per channel
// Z[c][y][x] = lms_e + i * fuse_e
// ---------------------------------------------------------------------------
__global__ __launch_bounds__(256) void blur_pack_kernel(
        const float* __restrict__ lms, const float* __restrict__ fuse,
        float2* __restrict__ Z) {
    __shared__ float sl[22][23];
    __shared__ float sf[22][23];
    int c = blockIdx.z;
    int bx = blockIdx.x * 16, by = blockIdx.y * 16;
    int tx = threadIdx.x, ty = threadIdx.y;
    int tid = ty * 16 + tx;
    const float* L = lms + ((size_t)c << 20);
    const float* F = fuse + ((size_t)c << 20);
    for (int i = tid; i < 22 * 22; i += 256) {
        int r = i / 22, cc = i - r * 22;
        int gy = by + r - 3, gx = bx + cc - 3;
        bool ok = (gy >= 0 && gy < SS && gx >= 0 && gx < SS);
        sl[r][cc] = ok ? L[gy * SS + gx] : 0.0f;
        sf[r][cc] = ok ? F[gy * SS + gx] : 0.0f;
    }
    __syncthreads();
    // Gaussian weights (sigma=1, ks=7), computed in double then cast
    double e1 = exp(-0.5), e2 = exp(-2.0), e3 = exp(-4.5);
    double sm = 1.0 + 2.0 * (e1 + e2 + e3);
    float w[7] = { (float)(e3 / sm), (float)(e2 / sm), (float)(e1 / sm),
                   (float)(1.0 / sm),
                   (float)(e1 / sm), (float)(e2 / sm), (float)(e3 / sm) };
    float bl = 0.0f, bf = 0.0f;
    #pragma unroll
    for (int i = 0; i < 7; ++i) {
        float rl = 0.0f, rf = 0.0f;
        #pragma unroll
        for (int j = 0; j < 7; ++j) {
            rl += w[j] * sl[ty + i][tx + j];
            rf += w[j] * sf[ty + i][tx + j];
        }
        bl += w[i] * rl;
        bf += w[i] * rf;
    }
    int y = by + ty, x = bx + tx;
    int gy = (y < BWD) ? y : ((SS - 1 - y) < BWD ? (SS - 1 - y) : -1);
    int gx = (x < BWD) ? x : ((SS - 1 - x) < BWD ? (SS - 1 - x) : -1);
    int m = gy > gx ? gy : gx;
    float a = (m >= 0) ? (float)m / (float)BWD : 1.0f;
    float cl = sl[ty + 3][tx + 3], cf = sf[ty + 3][tx + 3];
    float ol = a * cl + (1.0f - a) * bl;
    float of = a * cf + (1.0f - a) * bf;
    Z[((size_t)c << 20) + ((size_t)y << 10) + x] = make_float2(ol, of);
}

// ---------------------------------------------------------------------------
// 1024-point Stockham radix-2 FFT in LDS. 256 threads, 2 butterflies each per
// stage. DIRSIGN = -1 forward (e^{-i}), +1 inverse (e^{+i}).
// ---------------------------------------------------------------------------
template <int DIRSIGN>
__device__ __forceinline__ float2* fft1024(float2* bufA, float2* bufB,
                                           float2* lut, int tid) {
    for (int i = tid; i < 512; i += 256) {
        float ang = (float)DIRSIGN * 6.28318530717958647692f * (float)i *
                    (1.0f / 1024.0f);
        float sv, cv;
        sincosf(ang, &sv, &cv);
        lut[i] = make_float2(cv, sv);
    }
    __syncthreads();  // covers caller's bufA fill + lut fill
    float2* src = bufA;
    float2* dst = bufB;
    for (int t = 0; t < 10; ++t) {
        int s = 1 << t;
        #pragma unroll
        for (int h = 0; h < 2; ++h) {
            int j = tid + (h << 8);
            float2 A = src[j];
            float2 B = src[j + 512];
            float2 sum = make_float2(A.x + B.x, A.y + B.y);
            float2 dif = make_float2(A.x - B.x, A.y - B.y);
            int q = j & (s - 1);
            float2 w = lut[j - q];
            int d0 = q + ((j >> t) << (t + 1));
            dst[d0] = sum;
            dst[d0 + s] = cmul(dif, w);
        }
        __syncthreads();
        float2* tmp = src; src = dst; dst = tmp;
    }
    return src;  // after 10 swaps result is back in bufA
}

template <int DIRSIGN>
__global__ __launch_bounds__(256) void fft_rows_kernel(float2* __restrict__ data,
                                                       float scale) {
    __shared__ float2 bufA[1024];
    __shared__ float2 bufB[1024];
    __shared__ float2 lut[512];
    int tid = threadIdx.x;
    size_t base = (size_t)blockIdx.x << 10;
    for (int k = tid; k < 1024; k += 256) bufA[k] = data[base + k];
    float2* res = fft1024<DIRSIGN>(bufA, bufB, lut, tid);
    for (int k = tid; k < 1024; k += 256) {
        float2 v = res[k];
        data[base + k] = make_float2(v.x * scale, v.y * scale);
    }
}

// Final inverse pass: FFT over rows, then fused 1/N scale + fftshift +
// threshold + split packed pair into two real psf planes.
__global__ __launch_bounds__(256) void ifft_final_kernel(
        const float2* __restrict__ Wd, float* __restrict__ psf) {
    __shared__ float2 bufA[1024];
    __shared__ float2 bufB[1024];
    __shared__ float2 lut[512];
    int tid = threadIdx.x;
    size_t base = (size_t)blockIdx.x << 10;
    for (int k = tid; k < 1024; k += 256) bufA[k] = Wd[base + k];
    float2* res = fft1024<1>(bufA, bufB, lut, tid);
    int p = blockIdx.x >> 10;
    int y = blockIdx.x & 1023;
    int oy = (y + 512) & 1023;
    float* p0 = psf + (((size_t)(2 * p) << 20) + ((size_t)oy << 10));
    float* p1 = p0 + (1u << 20);
    const float sc = 1.0f / 1024.0f;
    for (int k = tid; k < 1024; k += 256) {
        float2 v = res[k];
        float re = v.x * sc; re = (re < THRESH) ? 0.0f : re;
        float im = v.y * sc; im = (im < THRESH) ? 0.0f : im;
        int ox = (k + 512) & 1023;
        p0[ox] = re;
        p1[ox] = im;
    }
}

// ---------------------------------------------------------------------------
// In-place square transpose, 32x32 tile pairs, per plane (grid.y = plane)
// ---------------------------------------------------------------------------
__global__ __launch_bounds__(256) void transpose_kernel(float2* __restrict__ A) {
    __shared__ float2 ta[32][33];
    __shared__ float2 tb[32][33];
    float2* P = A + ((size_t)blockIdx.y << 20);
    int r = blockIdx.x, bi = 0;
    while (r >= 32 - bi) { r -= 32 - bi; ++bi; }
    int bj = bi + r;
    int tx = threadIdx.x & 31, ty = threadIdx.x >> 5;
    for (int yy = ty; yy < 32; yy += 8) {
        ta[yy][tx] = P[(size_t)(bi * 32 + yy) * SS + bj * 32 + tx];
        tb[yy][tx] = P[(size_t)(bj * 32 + yy) * SS + bi * 32 + tx];
    }
    __syncthreads();
    for (int yy = ty; yy < 32; yy += 8) {
        P[(size_t)(bi * 32 + yy) * SS + bj * 32 + tx] = tb[tx][yy];
        P[(size_t)(bj * 32 + yy) * SS + bi * 32 + tx] = ta[tx][yy];
    }
}

// ---------------------------------------------------------------------------
// Wiener pointwise in transposed spectral layout [u=kx][v=ky].
// Unpack L,F from Hermitian symmetry of packed Z; pack G pairs: W = G0 + i*G1
// ---------------------------------------------------------------------------
__global__ __launch_bounds__(256) void wiener_kernel(
        const float2* __restrict__ Z, float2* __restrict__ W) {
    size_t gid = ((size_t)blockIdx.x << 8) + threadIdx.x;
    int p = (int)(gid >> 20);
    int uv = (int)(gid & 1048575);
    int u = uv >> 10, v = uv & 1023;
    int un = (1024 - u) & 1023, vn = (1024 - v) & 1023;
    const float TPN = 6.28318530717958647692f / 1024.0f;
    float cu = cosf(TPN * (float)u);
    float cv = cosf(TPN * (float)v);
    float c2u = 2.0f * cu * cu - 1.0f;
    float c2v = 2.0f * cv * cv - 1.0f;
    float hu = 2.0f + 2.0f * cu;
    float hv = 2.0f + 2.0f * cv;
    // grad(ky=v, kx=u) = |Gv|^2 + |Gh|^2 (symmetric under transpose)
    float grad = (2.0f - 2.0f * c2v) * hu * hu + (2.0f - 2.0f * c2u) * hv * hv;
    float regs = 5.0f + 5.0f * grad;
    float G0x, G0y, G1x, G1y;
    #pragma unroll
    for (int c = 0; c < 2; ++c) {
        const float2* Zc = Z + ((size_t)(2 * p + c) << 20);
        float2 a = Zc[(u << 10) + v];
        float2 b = Zc[(un << 10) + vn];
        // L = (Z(k)+conj(Z(-k)))/2 ; F = -i/2 (Z(k)-conj(Z(-k)))
        float Lx = 0.5f * (a.x + b.x), Ly = 0.5f * (a.y - b.y);
        float Fx = 0.5f * (a.y + b.y), Fy = -0.5f * (a.x - b.x);
        float denom = Fx * Fx + Fy * Fy + regs;
        float inv = 1.0f / denom;
        float nx = (Fx * Lx + Fy * Ly) * inv;   // conj(F)*L
        float ny = (Fx * Ly - Fy * Lx) * inv;
        if (c == 0) { G0x = nx; G0y = ny; } else { G1x = nx; G1y = ny; }
    }
    W[gid] = make_float2(G0x - G1y, G0y + G1x);
}

// ---------------------------------------------------------------------------
// Argmax per channel: encode (float bits << 32) | (~idx); floats >= 0 so bit
// pattern is order-preserving; ~idx gives first-occurrence tie-break.
// ---------------------------------------------------------------------------
__global__ void argmax_init_kernel(ull* am) {
    if (threadIdx.x < NC) am[threadIdx.x] = 0ull;
}

__global__ __launch_bounds__(256) void argmax_kernel(
        const float* __restrict__ psf, ull* __restrict__ am) {
    int c = blockIdx.y;
    const float* p = psf + ((size_t)c << 20);
    float best = 0.0f;
    unsigned int bidx = 0;
    for (unsigned int i = blockIdx.x * 256 + threadIdx.x; i < (1u << 20);
         i += gridDim.x * 256) {
        float v = p[i];
        if (v > best) { best = v; bidx = i; }
    }
    ull e = ((ull)__float_as_uint(best) << 32) |
            (ull)(0xFFFFFFFFu - bidx);
    __shared__ ull red[256];
    red[threadIdx.x] = e;
    __syncthreads();
    for (int s2 = 128; s2 > 0; s2 >>= 1) {
        if (threadIdx.x < s2) {
            ull x0 = red[threadIdx.x], x1 = red[threadIdx.x + s2];
            red[threadIdx.x] = x0 > x1 ? x0 : x1;
        }
        __syncthreads();
    }
    if (threadIdx.x == 0) atomicMax(&am[c], red[0]);
}

// ---------------------------------------------------------------------------
// Crop 41x41 around argmax (dynamic_slice clamp semantics) + normalize
// ---------------------------------------------------------------------------
__global__ __launch_bounds__(256) void crop_kernel(
        const float* __restrict__ psf, const ull* __restrict__ am,
        float* __restrict__ out) {
    int c = blockIdx.x;
    ull e = am[c];
    unsigned int bidx = 0xFFFFFFFFu - (unsigned int)(e & 0xFFFFFFFFull);
    int row = (int)(bidx >> 10), col = (int)(bidx & 1023);
    int r0 = row - 20; if (r0 < 0) r0 = 0; if (r0 > SS - 41) r0 = SS - 41;
    int c0 = col - 20; if (c0 < 0) c0 = 0; if (c0 > SS - 41) c0 = SS - 41;
    const float* p = psf + ((size_t)c << 20);
    float local = 0.0f;
    for (int i = threadIdx.x; i < 1681; i += 256) {
        int rr = i / 41, cc = i - rr * 41;
        local += p[(size_t)(r0 + rr) * SS + c0 + cc];
    }
    __shared__ float red[256];
    red[threadIdx.x] = local;
    __syncthreads();
    for (int s2 = 128; s2 > 0; s2 >>= 1) {
        if (threadIdx.x < s2) red[threadIdx.x] += red[threadIdx.x + s2];
        __syncthreads();
    }
    float inv = 1.0f / red[0];
    for (int i = threadIdx.x; i < 1681; i += 256) {
        int rr = i / 41, cc = i - rr * 41;
        out[c * 1681 + i] = p[(size_t)(r0 + rr) * SS + c0 + cc] * inv;
    }
}

// ---------------------------------------------------------------------------
extern "C" void kernel_launch(void* const* d_in, const int* in_sizes, int n_in,
                              void* d_out, int out_size, void* d_ws,
                              size_t ws_size, hipStream_t stream) {
    const float* lms = (const float*)d_in[0];
    const float* fuse = (const float*)d_in[1];
    char* ws = (char*)d_ws;
    float2* Zf = (float2*)ws;                                   // 64 MB: 8 planes
    float2* Wb = (float2*)(ws + ((size_t)64 << 20));            // 32 MB: 4 planes
    float* psf = (float*)ws;                                    // 32 MB, reuses Zf
    ull* am = (ull*)(ws + ((size_t)33 << 20));                  // in dead Zf region
    float* outp = (float*)d_out;

    // 1. blur + alpha blend + pack
    blur_pack_kernel<<<dim3(64, 64, 8), dim3(16, 16), 0, stream>>>(lms, fuse, Zf);
    // 2. forward FFT2 (rows, transpose, rows) -> spectrum in [kx][ky] layout
    fft_rows_kernel<-1><<<8192, 256, 0, stream>>>(Zf, 1.0f);
    transpose_kernel<<<dim3(528, 8), 256, 0, stream>>>(Zf);
    fft_rows_kernel<-1><<<8192, 256, 0, stream>>>(Zf, 1.0f);
    // 3. Wiener pointwise, pack channel pairs
    wiener_kernel<<<16384, 256, 0, stream>>>(Zf, Wb);
    argmax_init_kernel<<<1, 64, 0, stream>>>(am);
    // 4. inverse FFT2 with fused shift/threshold/split on last pass
    fft_rows_kernel<1><<<4096, 256, 0, stream>>>(Wb, 1.0f / 1024.0f);
    transpose_kernel<<<dim3(528, 4), 256, 0, stream>>>(Wb);
    ifft_final_kernel<<<4096, 256, 0, stream>>>(Wb, psf);
    // 5. argmax + crop/normalize
    argmax_kernel<<<dim3(64, 8), 256, 0, stream>>>(psf, am);
    crop_kernel<<<8, 256, 0, stream>>>(psf, am, outp);
}

// Round 2
// 328.898 us; speedup vs baseline: 1.3027x; 1.3027x over previous
//
#include <hip/hip_runtime.h>
#include <math.h>

#define SS 1024
#define NC 8
#define BWD 170
#define THRESH 1e-4f

typedef unsigned long long ull;

__device__ __forceinline__ float2 cmul(float2 a, float2 b) {
    return make_float2(a.x * b.x - a.y * b.y, a.x * b.y + a.y * b.x);
}

// ---------------------------------------------------------------------------
// Blur + alpha blend + pack. Two-stage separable filter, 32x32 output tile,
// interior (alpha==1) fast path. Z[c][y][x] = lms_e + i * fuse_e
// ---------------------------------------------------------------------------
__global__ __launch_bounds__(256) void blur_pack_kernel(
        const float* __restrict__ lms, const float* __restrict__ fuse,
        float2* __restrict__ Z) {
    int c = blockIdx.z;
    int bx = blockIdx.x * 32, by = blockIdx.y * 32;
    int tid = threadIdx.x;
    const float* L = lms + ((size_t)c << 20);
    const float* F = fuse + ((size_t)c << 20);
    float2* Zc = Z + ((size_t)c << 20);

    // alpha==1 iff row,col in [BWD, SS-1-BWD]; block-uniform fast path
    bool fast = (bx >= BWD) && (bx + 31 <= SS - 1 - BWD) &&
                (by >= BWD) && (by + 31 <= SS - 1 - BWD);
    if (fast) {
        int r = tid >> 3, g = (tid & 7) * 4;
        int y = by + r, x = bx + g;
        float4 lv = *(const float4*)&L[((size_t)y << 10) + x];
        float4 fv = *(const float4*)&F[((size_t)y << 10) + x];
        float2* zp = &Zc[((size_t)y << 10) + x];
        *(float4*)&zp[0] = make_float4(lv.x, fv.x, lv.y, fv.y);
        *(float4*)&zp[2] = make_float4(lv.z, fv.z, lv.w, fv.w);
        return;
    }

    __shared__ float sl[38][40];   // halo input, stride 40 -> <=2-way banks
    __shared__ float sf[38][40];
    __shared__ float hl[38][33];   // horizontal-blurred intermediate
    __shared__ float hf[38][33];

    // halo load: rows [by-3, by+35), cols [bx-3, bx+35), zero-pad OOB
    for (int i = tid; i < 38 * 38; i += 256) {
        int r = i / 38, cc = i - r * 38;
        int gy = by + r - 3, gx = bx + cc - 3;
        bool ok = (gy >= 0 && gy < SS && gx >= 0 && gx < SS);
        size_t off = ((size_t)gy << 10) + gx;
        sl[r][cc] = ok ? L[off] : 0.0f;
        sf[r][cc] = ok ? F[off] : 0.0f;
    }
    __syncthreads();

    // Gaussian weights (sigma=1, ks=7)
    double e1 = exp(-0.5), e2 = exp(-2.0), e3 = exp(-4.5);
    double sm = 1.0 + 2.0 * (e1 + e2 + e3);
    float w[7] = { (float)(e3 / sm), (float)(e2 / sm), (float)(e1 / sm),
                   (float)(1.0 / sm),
                   (float)(e1 / sm), (float)(e2 / sm), (float)(e3 / sm) };

    // stage 1: horizontal blur. 38 rows x 8 groups of 4 cols = 304 tasks
    for (int t = tid; t < 304; t += 256) {
        int r = t >> 3, g = (t & 7) * 4;
        float a[10], b[10];
        #pragma unroll
        for (int j = 0; j < 10; ++j) { a[j] = sl[r][g + j]; b[j] = sf[r][g + j]; }
        #pragma unroll
        for (int k = 0; k < 4; ++k) {
            float ol = 0.0f, of = 0.0f;
            #pragma unroll
            for (int j = 0; j < 7; ++j) { ol += w[j] * a[k + j]; of += w[j] * b[k + j]; }
            hl[r][g + k] = ol;
            hf[r][g + k] = of;
        }
    }
    __syncthreads();

    // stage 2: vertical blur + alpha blend + packed store.
    // 8 row-groups x 32 cols = 256 tasks, exactly one per thread.
    {
        int col = tid & 31, rg = (tid >> 5) * 4;
        int x = bx + col;
        float vl[10], vf[10];
        #pragma unroll
        for (int j = 0; j < 10; ++j) { vl[j] = hl[rg + j][col]; vf[j] = hf[rg + j][col]; }
        int gx = (x < BWD) ? x : ((SS - 1 - x) < BWD ? (SS - 1 - x) : -1);
        #pragma unroll
        for (int k = 0; k < 4; ++k) {
            int oy = rg + k, y = by + oy;
            float bl = 0.0f, bf = 0.0f;
            #pragma unroll
            for (int j = 0; j < 7; ++j) { bl += w[j] * vl[k + j]; bf += w[j] * vf[k + j]; }
            int gy = (y < BWD) ? y : ((SS - 1 - y) < BWD ? (SS - 1 - y) : -1);
            int m = gy > gx ? gy : gx;
            float a = (m >= 0) ? (float)m / (float)BWD : 1.0f;
            float cl = sl[oy + 3][col + 3], cf = sf[oy + 3][col + 3];
            Zc[((size_t)y << 10) + x] =
                make_float2(a * cl + (1.0f - a) * bl, a * cf + (1.0f - a) * bf);
        }
    }
}

// ---------------------------------------------------------------------------
// 1024-point Stockham radix-2 FFT in LDS. 256 threads, 2 butterflies each per
// stage. DIRSIGN = -1 forward (e^{-i}), +1 inverse (e^{+i}).
// ---------------------------------------------------------------------------
template <int DIRSIGN>
__device__ __forceinline__ float2* fft1024(float2* bufA, float2* bufB,
                                           float2* lut, int tid) {
    for (int i = tid; i < 512; i += 256) {
        float ang = (float)DIRSIGN * 6.28318530717958647692f * (float)i *
                    (1.0f / 1024.0f);
        float sv, cv;
        sincosf(ang, &sv, &cv);
        lut[i] = make_float2(cv, sv);
    }
    __syncthreads();  // covers caller's bufA fill + lut fill
    float2* src = bufA;
    float2* dst = bufB;
    for (int t = 0; t < 10; ++t) {
        int s = 1 << t;
        #pragma unroll
        for (int h = 0; h < 2; ++h) {
            int j = tid + (h << 8);
            float2 A = src[j];
            float2 B = src[j + 512];
            float2 sum = make_float2(A.x + B.x, A.y + B.y);
            float2 dif = make_float2(A.x - B.x, A.y - B.y);
            int q = j & (s - 1);
            float2 w = lut[j - q];
            int d0 = q + ((j >> t) << (t + 1));
            dst[d0] = sum;
            dst[d0 + s] = cmul(dif, w);
        }
        __syncthreads();
        float2* tmp = src; src = dst; dst = tmp;
    }
    return src;  // after 10 swaps result is back in bufA
}

template <int DIRSIGN>
__global__ __launch_bounds__(256) void fft_rows_kernel(float2* __restrict__ data,
                                                       float scale) {
    __shared__ float2 bufA[1024];
    __shared__ float2 bufB[1024];
    __shared__ float2 lut[512];
    int tid = threadIdx.x;
    size_t base = (size_t)blockIdx.x << 10;
    for (int k = tid; k < 1024; k += 256) bufA[k] = data[base + k];
    float2* res = fft1024<DIRSIGN>(bufA, bufB, lut, tid);
    for (int k = tid; k < 1024; k += 256) {
        float2 v = res[k];
        data[base + k] = make_float2(v.x * scale, v.y * scale);
    }
}

// Final inverse pass: FFT over rows, then fused 1/N scale + fftshift +
// threshold + split packed pair into two real psf planes.
__global__ __launch_bounds__(256) void ifft_final_kernel(
        const float2* __restrict__ Wd, float* __restrict__ psf) {
    __shared__ float2 bufA[1024];
    __shared__ float2 bufB[1024];
    __shared__ float2 lut[512];
    int tid = threadIdx.x;
    size_t base = (size_t)blockIdx.x << 10;
    for (int k = tid; k < 1024; k += 256) bufA[k] = Wd[base + k];
    float2* res = fft1024<1>(bufA, bufB, lut, tid);
    int p = blockIdx.x >> 10;
    int y = blockIdx.x & 1023;
    int oy = (y + 512) & 1023;
    float* p0 = psf + (((size_t)(2 * p) << 20) + ((size_t)oy << 10));
    float* p1 = p0 + (1u << 20);
    const float sc = 1.0f / 1024.0f;
    for (int k = tid; k < 1024; k += 256) {
        float2 v = res[k];
        float re = v.x * sc; re = (re < THRESH) ? 0.0f : re;
        float im = v.y * sc; im = (im < THRESH) ? 0.0f : im;
        int ox = (k + 512) & 1023;
        p0[ox] = re;
        p1[ox] = im;
    }
}

// ---------------------------------------------------------------------------
// In-place square transpose, 32x32 tile pairs, per plane (grid.y = plane)
// ---------------------------------------------------------------------------
__global__ __launch_bounds__(256) void transpose_kernel(float2* __restrict__ A) {
    __shared__ float2 ta[32][33];
    __shared__ float2 tb[32][33];
    float2* P = A + ((size_t)blockIdx.y << 20);
    int r = blockIdx.x, bi = 0;
    while (r >= 32 - bi) { r -= 32 - bi; ++bi; }
    int bj = bi + r;
    int tx = threadIdx.x & 31, ty = threadIdx.x >> 5;
    for (int yy = ty; yy < 32; yy += 8) {
        ta[yy][tx] = P[(size_t)(bi * 32 + yy) * SS + bj * 32 + tx];
        tb[yy][tx] = P[(size_t)(bj * 32 + yy) * SS + bi * 32 + tx];
    }
    __syncthreads();
    for (int yy = ty; yy < 32; yy += 8) {
        P[(size_t)(bi * 32 + yy) * SS + bj * 32 + tx] = tb[tx][yy];
        P[(size_t)(bj * 32 + yy) * SS + bi * 32 + tx] = ta[tx][yy];
    }
}

// ---------------------------------------------------------------------------
// Wiener pointwise in transposed spectral layout [u=kx][v=ky].
// Unpack L,F from Hermitian symmetry of packed Z; pack G pairs: W = G0 + i*G1
// ---------------------------------------------------------------------------
__global__ __launch_bounds__(256) void wiener_kernel(
        const float2* __restrict__ Z, float2* __restrict__ W) {
    size_t gid = ((size_t)blockIdx.x << 8) + threadIdx.x;
    int p = (int)(gid >> 20);
    int uv = (int)(gid & 1048575);
    int u = uv >> 10, v = uv & 1023;
    int un = (1024 - u) & 1023, vn = (1024 - v) & 1023;
    const float TPN = 6.28318530717958647692f / 1024.0f;
    float cu = cosf(TPN * (float)u);
    float cv = cosf(TPN * (float)v);
    float c2u = 2.0f * cu * cu - 1.0f;
    float c2v = 2.0f * cv * cv - 1.0f;
    float hu = 2.0f + 2.0f * cu;
    float hv = 2.0f + 2.0f * cv;
    // grad(ky=v, kx=u) = |Gv|^2 + |Gh|^2 (symmetric under transpose)
    float grad = (2.0f - 2.0f * c2v) * hu * hu + (2.0f - 2.0f * c2u) * hv * hv;
    float regs = 5.0f + 5.0f * grad;
    float G0x, G0y, G1x, G1y;
    #pragma unroll
    for (int c = 0; c < 2; ++c) {
        const float2* Zc = Z + ((size_t)(2 * p + c) << 20);
        float2 a = Zc[(u << 10) + v];
        float2 b = Zc[(un << 10) + vn];
        // L = (Z(k)+conj(Z(-k)))/2 ; F = -i/2 (Z(k)-conj(Z(-k)))
        float Lx = 0.5f * (a.x + b.x), Ly = 0.5f * (a.y - b.y);
        float Fx = 0.5f * (a.y + b.y), Fy = -0.5f * (a.x - b.x);
        float denom = Fx * Fx + Fy * Fy + regs;
        float inv = 1.0f / denom;
        float nx = (Fx * Lx + Fy * Ly) * inv;   // conj(F)*L
        float ny = (Fx * Ly - Fy * Lx) * inv;
        if (c == 0) { G0x = nx; G0y = ny; } else { G1x = nx; G1y = ny; }
    }
    W[gid] = make_float2(G0x - G1y, G0y + G1x);
}

// ---------------------------------------------------------------------------
// Argmax per channel: encode (float bits << 32) | (~idx); floats >= 0 so bit
// pattern is order-preserving; ~idx gives first-occurrence tie-break.
// ---------------------------------------------------------------------------
__global__ void argmax_init_kernel(ull* am) {
    if (threadIdx.x < NC) am[threadIdx.x] = 0ull;
}

__global__ __launch_bounds__(256) void argmax_kernel(
        const float* __restrict__ psf, ull* __restrict__ am) {
    int c = blockIdx.y;
    const float* p = psf + ((size_t)c << 20);
    float best = 0.0f;
    unsigned int bidx = 0;
    for (unsigned int i = blockIdx.x * 256 + threadIdx.x; i < (1u << 20);
         i += gridDim.x * 256) {
        float v = p[i];
        if (v > best) { best = v; bidx = i; }
    }
    ull e = ((ull)__float_as_uint(best) << 32) |
            (ull)(0xFFFFFFFFu - bidx);
    __shared__ ull red[256];
    red[threadIdx.x] = e;
    __syncthreads();
    for (int s2 = 128; s2 > 0; s2 >>= 1) {
        if (threadIdx.x < s2) {
            ull x0 = red[threadIdx.x], x1 = red[threadIdx.x + s2];
            red[threadIdx.x] = x0 > x1 ? x0 : x1;
        }
        __syncthreads();
    }
    if (threadIdx.x == 0) atomicMax(&am[c], red[0]);
}

// ---------------------------------------------------------------------------
// Crop 41x41 around argmax (dynamic_slice clamp semantics) + normalize
// ---------------------------------------------------------------------------
__global__ __launch_bounds__(256) void crop_kernel(
        const float* __restrict__ psf, const ull* __restrict__ am,
        float* __restrict__ out) {
    int c = blockIdx.x;
    ull e = am[c];
    unsigned int bidx = 0xFFFFFFFFu - (unsigned int)(e & 0xFFFFFFFFull);
    int row = (int)(bidx >> 10), col = (int)(bidx & 1023);
    int r0 = row - 20; if (r0 < 0) r0 = 0; if (r0 > SS - 41) r0 = SS - 41;
    int c0 = col - 20; if (c0 < 0) c0 = 0; if (c0 > SS - 41) c0 = SS - 41;
    const float* p = psf + ((size_t)c << 20);
    float local = 0.0f;
    for (int i = threadIdx.x; i < 1681; i += 256) {
        int rr = i / 41, cc = i - rr * 41;
        local += p[(size_t)(r0 + rr) * SS + c0 + cc];
    }
    __shared__ float red[256];
    red[threadIdx.x] = local;
    __syncthreads();
    for (int s2 = 128; s2 > 0; s2 >>= 1) {
        if (threadIdx.x < s2) red[threadIdx.x] += red[threadIdx.x + s2];
        __syncthreads();
    }
    float inv = 1.0f / red[0];
    for (int i = threadIdx.x; i < 1681; i += 256) {
        int rr = i / 41, cc = i - rr * 41;
        out[c * 1681 + i] = p[(size_t)(r0 + rr) * SS + c0 + cc] * inv;
    }
}

// ---------------------------------------------------------------------------
extern "C" void kernel_launch(void* const* d_in, const int* in_sizes, int n_in,
                              void* d_out, int out_size, void* d_ws,
                              size_t ws_size, hipStream_t stream) {
    const float* lms = (const float*)d_in[0];
    const float* fuse = (const float*)d_in[1];
    char* ws = (char*)d_ws;
    float2* Zf = (float2*)ws;                                   // 64 MB: 8 planes
    float2* Wb = (float2*)(ws + ((size_t)64 << 20));            // 32 MB: 4 planes
    float* psf = (float*)ws;                                    // 32 MB, reuses Zf
    ull* am = (ull*)(ws + ((size_t)33 << 20));                  // in dead Zf region
    float* outp = (float*)d_out;

    // 1. blur + alpha blend + pack
    blur_pack_kernel<<<dim3(32, 32, 8), 256, 0, stream>>>(lms, fuse, Zf);
    // 2. forward FFT2 (rows, transpose, rows) -> spectrum in [kx][ky] layout
    fft_rows_kernel<-1><<<8192, 256, 0, stream>>>(Zf, 1.0f);
    transpose_kernel<<<dim3(528, 8), 256, 0, stream>>>(Zf);
    fft_rows_kernel<-1><<<8192, 256, 0, stream>>>(Zf, 1.0f);
    // 3. Wiener pointwise, pack channel pairs
    wiener_kernel<<<16384, 256, 0, stream>>>(Zf, Wb);
    argmax_init_kernel<<<1, 64, 0, stream>>>(am);
    // 4. inverse FFT2 with fused shift/threshold/split on last pass
    fft_rows_kernel<1><<<4096, 256, 0, stream>>>(Wb, 1.0f / 1024.0f);
    transpose_kernel<<<dim3(528, 4), 256, 0, stream>>>(Wb);
    ifft_final_kernel<<<4096, 256, 0, stream>>>(Wb, psf);
    // 5. argmax + crop/normalize
    argmax_kernel<<<dim3(64, 8), 256, 0, stream>>>(psf, am);
    crop_kernel<<<8, 256, 0, stream>>>(psf, am, outp);
}

// Round 3
// 294.339 us; speedup vs baseline: 1.4557x; 1.1174x over previous
//
#include <hip/hip_runtime.h>
#include <math.h>

#define SS 1024
#define NC 8
#define BWD 170
#define THRESH 1e-4f

typedef unsigned long long ull;

__device__ __forceinline__ float2 cmul(float2 a, float2 b) {
    return make_float2(a.x * b.x - a.y * b.y, a.x * b.y + a.y * b.x);
}

// ---------------------------------------------------------------------------
// Blur + alpha blend + pack. Two-stage separable filter, 32x32 output tile,
// interior (alpha==1) fast path. Z[c][y][x] = lms_e + i * fuse_e
// ---------------------------------------------------------------------------
__global__ __launch_bounds__(256) void blur_pack_kernel(
        const float* __restrict__ lms, const float* __restrict__ fuse,
        float2* __restrict__ Z) {
    int c = blockIdx.z;
    int bx = blockIdx.x * 32, by = blockIdx.y * 32;
    int tid = threadIdx.x;
    const float* L = lms + ((size_t)c << 20);
    const float* F = fuse + ((size_t)c << 20);
    float2* Zc = Z + ((size_t)c << 20);

    // alpha==1 iff row,col in [BWD, SS-1-BWD]; block-uniform fast path
    bool fast = (bx >= BWD) && (bx + 31 <= SS - 1 - BWD) &&
                (by >= BWD) && (by + 31 <= SS - 1 - BWD);
    if (fast) {
        int r = tid >> 3, g = (tid & 7) * 4;
        int y = by + r, x = bx + g;
        float4 lv = *(const float4*)&L[((size_t)y << 10) + x];
        float4 fv = *(const float4*)&F[((size_t)y << 10) + x];
        float2* zp = &Zc[((size_t)y << 10) + x];
        *(float4*)&zp[0] = make_float4(lv.x, fv.x, lv.y, fv.y);
        *(float4*)&zp[2] = make_float4(lv.z, fv.z, lv.w, fv.w);
        return;
    }

    __shared__ float sl[38][40];   // halo input, stride 40 -> <=2-way banks
    __shared__ float sf[38][40];
    __shared__ float hl[38][33];   // horizontal-blurred intermediate
    __shared__ float hf[38][33];

    // halo load: rows [by-3, by+35), cols [bx-3, bx+35), zero-pad OOB
    for (int i = tid; i < 38 * 38; i += 256) {
        int r = i / 38, cc = i - r * 38;
        int gy = by + r - 3, gx = bx + cc - 3;
        bool ok = (gy >= 0 && gy < SS && gx >= 0 && gx < SS);
        size_t off = ((size_t)gy << 10) + gx;
        sl[r][cc] = ok ? L[off] : 0.0f;
        sf[r][cc] = ok ? F[off] : 0.0f;
    }
    __syncthreads();

    // Gaussian weights (sigma=1, ks=7)
    double e1 = exp(-0.5), e2 = exp(-2.0), e3 = exp(-4.5);
    double sm = 1.0 + 2.0 * (e1 + e2 + e3);
    float w[7] = { (float)(e3 / sm), (float)(e2 / sm), (float)(e1 / sm),
                   (float)(1.0 / sm),
                   (float)(e1 / sm), (float)(e2 / sm), (float)(e3 / sm) };

    // stage 1: horizontal blur. 38 rows x 8 groups of 4 cols = 304 tasks
    for (int t = tid; t < 304; t += 256) {
        int r = t >> 3, g = (t & 7) * 4;
        float a[10], b[10];
        #pragma unroll
        for (int j = 0; j < 10; ++j) { a[j] = sl[r][g + j]; b[j] = sf[r][g + j]; }
        #pragma unroll
        for (int k = 0; k < 4; ++k) {
            float ol = 0.0f, of = 0.0f;
            #pragma unroll
            for (int j = 0; j < 7; ++j) { ol += w[j] * a[k + j]; of += w[j] * b[k + j]; }
            hl[r][g + k] = ol;
            hf[r][g + k] = of;
        }
    }
    __syncthreads();

    // stage 2: vertical blur + alpha blend + packed store.
    {
        int col = tid & 31, rg = (tid >> 5) * 4;
        int x = bx + col;
        float vl[10], vf[10];
        #pragma unroll
        for (int j = 0; j < 10; ++j) { vl[j] = hl[rg + j][col]; vf[j] = hf[rg + j][col]; }
        int gx = (x < BWD) ? x : ((SS - 1 - x) < BWD ? (SS - 1 - x) : -1);
        #pragma unroll
        for (int k = 0; k < 4; ++k) {
            int oy = rg + k, y = by + oy;
            float bl = 0.0f, bf = 0.0f;
            #pragma unroll
            for (int j = 0; j < 7; ++j) { bl += w[j] * vl[k + j]; bf += w[j] * vf[k + j]; }
            int gy = (y < BWD) ? y : ((SS - 1 - y) < BWD ? (SS - 1 - y) : -1);
            int m = gy > gx ? gy : gx;
            float a = (m >= 0) ? (float)m / (float)BWD : 1.0f;
            float cl = sl[oy + 3][col + 3], cf = sf[oy + 3][col + 3];
            Zc[((size_t)y << 10) + x] =
                make_float2(a * cl + (1.0f - a) * bl, a * cf + (1.0f - a) * bf);
        }
    }
}

// ---------------------------------------------------------------------------
// 1024-point Stockham RADIX-4 FFT in LDS. 256 threads, 1 radix-4 butterfly
// each per stage (5 stages). Reads at tid+{0,256,512,768} are lane-consecutive
// (2-way bank aliasing = free). DIRSIGN=-1 fwd, +1 inv.
// lut[k] = exp(DIRSIGN * 2*pi*i*k/1024), k in [0,768)
// ---------------------------------------------------------------------------
template <int DIRSIGN>
__device__ __forceinline__ float2* fft1024(float2* bufA, float2* bufB,
                                           float2* lut, int tid) {
    for (int i = tid; i < 768; i += 256) {
        float ang = (float)DIRSIGN * 6.28318530717958647692f * (float)i *
                    (1.0f / 1024.0f);
        float sv, cv;
        sincosf(ang, &sv, &cv);
        lut[i] = make_float2(cv, sv);
    }
    __syncthreads();  // covers caller's bufA fill + lut fill
    float2* src = bufA;
    float2* dst = bufB;
    #pragma unroll
    for (int t = 0; t < 5; ++t) {
        int s = 1 << (2 * t);
        int k = tid & ~(s - 1);           // p*s, twiddle index
        float2 a = src[tid];
        float2 b = src[tid + 256];
        float2 c = src[tid + 512];
        float2 d = src[tid + 768];
        float2 apc = make_float2(a.x + c.x, a.y + c.y);
        float2 amc = make_float2(a.x - c.x, a.y - c.y);
        float2 bpd = make_float2(b.x + d.x, b.y + d.y);
        float2 jb  = make_float2(-(b.y - d.y), b.x - d.x);   // i*(b-d)
        float2 t1, t3;
        if (DIRSIGN == -1) {
            t1 = make_float2(amc.x - jb.x, amc.y - jb.y);
            t3 = make_float2(amc.x + jb.x, amc.y + jb.y);
        } else {
            t1 = make_float2(amc.x + jb.x, amc.y + jb.y);
            t3 = make_float2(amc.x - jb.x, amc.y - jb.y);
        }
        float2 w1 = lut[k], w2 = lut[2 * k], w3 = lut[3 * k];
        int base = tid + 3 * k;           // q + 4*s*p
        dst[base]         = make_float2(apc.x + bpd.x, apc.y + bpd.y);
        dst[base + s]     = cmul(t1, w1);
        dst[base + 2 * s] = cmul(make_float2(apc.x - bpd.x, apc.y - bpd.y), w2);
        dst[base + 3 * s] = cmul(t3, w3);
        __syncthreads();
        float2* tmp = src; src = dst; dst = tmp;
    }
    return src;  // after 5 swaps, result is here (bufB)
}

template <int DIRSIGN>
__global__ __launch_bounds__(256) void fft_rows_kernel(float2* __restrict__ data,
                                                       float scale) {
    __shared__ float2 bufA[1024];
    __shared__ float2 bufB[1024];
    __shared__ float2 lut[768];
    int tid = threadIdx.x;
    size_t base = (size_t)blockIdx.x << 10;
    const float4* g = (const float4*)(data + base);
    #pragma unroll
    for (int h = 0; h < 2; ++h) {
        float4 v = g[tid + (h << 8)];
        int k = (tid + (h << 8)) << 1;
        bufA[k]     = make_float2(v.x, v.y);
        bufA[k + 1] = make_float2(v.z, v.w);
    }
    float2* res = fft1024<DIRSIGN>(bufA, bufB, lut, tid);
    float4* go = (float4*)(data + base);
    #pragma unroll
    for (int h = 0; h < 2; ++h) {
        int k = (tid + (h << 8)) << 1;
        float2 v0 = res[k], v1 = res[k + 1];
        go[tid + (h << 8)] = make_float4(v0.x * scale, v0.y * scale,
                                         v1.x * scale, v1.y * scale);
    }
}

// Final inverse pass: FFT over rows, then fused 1/N scale + fftshift +
// threshold + split packed pair into two real psf planes.
__global__ __launch_bounds__(256) void ifft_final_kernel(
        const float2* __restrict__ Wd, float* __restrict__ psf) {
    __shared__ float2 bufA[1024];
    __shared__ float2 bufB[1024];
    __shared__ float2 lut[768];
    int tid = threadIdx.x;
    size_t base = (size_t)blockIdx.x << 10;
    const float4* g = (const float4*)(Wd + base);
    #pragma unroll
    for (int h = 0; h < 2; ++h) {
        float4 v = g[tid + (h << 8)];
        int k = (tid + (h << 8)) << 1;
        bufA[k]     = make_float2(v.x, v.y);
        bufA[k + 1] = make_float2(v.z, v.w);
    }
    float2* res = fft1024<1>(bufA, bufB, lut, tid);
    int p = blockIdx.x >> 10;
    int y = blockIdx.x & 1023;
    int oy = (y + 512) & 1023;
    float* p0 = psf + (((size_t)(2 * p) << 20) + ((size_t)oy << 10));
    float* p1 = p0 + (1u << 20);
    const float sc = 1.0f / 1024.0f;
    for (int k = tid; k < 1024; k += 256) {
        float2 v = res[k];
        float re = v.x * sc; re = (re < THRESH) ? 0.0f : re;
        float im = v.y * sc; im = (im < THRESH) ? 0.0f : im;
        int ox = (k + 512) & 1023;
        p0[ox] = re;
        p1[ox] = im;
    }
}

// ---------------------------------------------------------------------------
// In-place square transpose, 32x32 tile pairs, per plane (grid.y = plane)
// ---------------------------------------------------------------------------
__global__ __launch_bounds__(256) void transpose_kernel(float2* __restrict__ A) {
    __shared__ float2 ta[32][33];
    __shared__ float2 tb[32][33];
    float2* P = A + ((size_t)blockIdx.y << 20);
    int r = blockIdx.x, bi = 0;
    while (r >= 32 - bi) { r -= 32 - bi; ++bi; }
    int bj = bi + r;
    int tx = threadIdx.x & 31, ty = threadIdx.x >> 5;
    for (int yy = ty; yy < 32; yy += 8) {
        ta[yy][tx] = P[(size_t)(bi * 32 + yy) * SS + bj * 32 + tx];
        tb[yy][tx] = P[(size_t)(bj * 32 + yy) * SS + bi * 32 + tx];
    }
    __syncthreads();
    for (int yy = ty; yy < 32; yy += 8) {
        P[(size_t)(bi * 32 + yy) * SS + bj * 32 + tx] = tb[tx][yy];
        P[(size_t)(bj * 32 + yy) * SS + bi * 32 + tx] = ta[tx][yy];
    }
}

// ---------------------------------------------------------------------------
// Wiener pointwise in transposed spectral layout [u=kx][v=ky].
// Unpack L,F from Hermitian symmetry of packed Z; pack G pairs: W = G0 + i*G1
// ---------------------------------------------------------------------------
__global__ __launch_bounds__(256) void wiener_kernel(
        const float2* __restrict__ Z, float2* __restrict__ W) {
    size_t gid = ((size_t)blockIdx.x << 8) + threadIdx.x;
    int p = (int)(gid >> 20);
    int uv = (int)(gid & 1048575);
    int u = uv >> 10, v = uv & 1023;
    int un = (1024 - u) & 1023, vn = (1024 - v) & 1023;
    const float TPN = 6.28318530717958647692f / 1024.0f;
    float cu = cosf(TPN * (float)u);
    float cv = cosf(TPN * (float)v);
    float c2u = 2.0f * cu * cu - 1.0f;
    float c2v = 2.0f * cv * cv - 1.0f;
    float hu = 2.0f + 2.0f * cu;
    float hv = 2.0f + 2.0f * cv;
    // grad(ky=v, kx=u) = |Gv|^2 + |Gh|^2 (symmetric under transpose)
    float grad = (2.0f - 2.0f * c2v) * hu * hu + (2.0f - 2.0f * c2u) * hv * hv;
    float regs = 5.0f + 5.0f * grad;
    float G0x, G0y, G1x, G1y;
    #pragma unroll
    for (int c = 0; c < 2; ++c) {
        const float2* Zc = Z + ((size_t)(2 * p + c) << 20);
        float2 a = Zc[(u << 10) + v];
        float2 b = Zc[(un << 10) + vn];
        // L = (Z(k)+conj(Z(-k)))/2 ; F = -i/2 (Z(k)-conj(Z(-k)))
        float Lx = 0.5f * (a.x + b.x), Ly = 0.5f * (a.y - b.y);
        float Fx = 0.5f * (a.y + b.y), Fy = -0.5f * (a.x - b.x);
        float denom = Fx * Fx + Fy * Fy + regs;
        float inv = 1.0f / denom;
        float nx = (Fx * Lx + Fy * Ly) * inv;   // conj(F)*L
        float ny = (Fx * Ly - Fy * Lx) * inv;
        if (c == 0) { G0x = nx; G0y = ny; } else { G1x = nx; G1y = ny; }
    }
    W[gid] = make_float2(G0x - G1y, G0y + G1x);
}

// ---------------------------------------------------------------------------
// Argmax per channel: encode (float bits << 32) | (~idx); floats >= 0 so bit
// pattern is order-preserving; ~idx gives first-occurrence tie-break.
// ---------------------------------------------------------------------------
__global__ void argmax_init_kernel(ull* am) {
    if (threadIdx.x < NC) am[threadIdx.x] = 0ull;
}

__global__ __launch_bounds__(256) void argmax_kernel(
        const float* __restrict__ psf, ull* __restrict__ am) {
    int c = blockIdx.y;
    const float* p = psf + ((size_t)c << 20);
    float best = 0.0f;
    unsigned int bidx = 0;
    for (unsigned int i = blockIdx.x * 256 + threadIdx.x; i < (1u << 20);
         i += gridDim.x * 256) {
        float v = p[i];
        if (v > best) { best = v; bidx = i; }
    }
    ull e = ((ull)__float_as_uint(best) << 32) |
            (ull)(0xFFFFFFFFu - bidx);
    __shared__ ull red[256];
    red[threadIdx.x] = e;
    __syncthreads();
    for (int s2 = 128; s2 > 0; s2 >>= 1) {
        if (threadIdx.x < s2) {
            ull x0 = red[threadIdx.x], x1 = red[threadIdx.x + s2];
            red[threadIdx.x] = x0 > x1 ? x0 : x1;
        }
        __syncthreads();
    }
    if (threadIdx.x == 0) atomicMax(&am[c], red[0]);
}

// ---------------------------------------------------------------------------
// Crop 41x41 around argmax (dynamic_slice clamp semantics) + normalize
// ---------------------------------------------------------------------------
__global__ __launch_bounds__(256) void crop_kernel(
        const float* __restrict__ psf, const ull* __restrict__ am,
        float* __restrict__ out) {
    int c = blockIdx.x;
    ull e = am[c];
    unsigned int bidx = 0xFFFFFFFFu - (unsigned int)(e & 0xFFFFFFFFull);
    int row = (int)(bidx >> 10), col = (int)(bidx & 1023);
    int r0 = row - 20; if (r0 < 0) r0 = 0; if (r0 > SS - 41) r0 = SS - 41;
    int c0 = col - 20; if (c0 < 0) c0 = 0; if (c0 > SS - 41) c0 = SS - 41;
    const float* p = psf + ((size_t)c << 20);
    float local = 0.0f;
    for (int i = threadIdx.x; i < 1681; i += 256) {
        int rr = i / 41, cc = i - rr * 41;
        local += p[(size_t)(r0 + rr) * SS + c0 + cc];
    }
    __shared__ float red[256];
    red[threadIdx.x] = local;
    __syncthreads();
    for (int s2 = 128; s2 > 0; s2 >>= 1) {
        if (threadIdx.x < s2) red[threadIdx.x] += red[threadIdx.x + s2];
        __syncthreads();
    }
    float inv = 1.0f / red[0];
    for (int i = threadIdx.x; i < 1681; i += 256) {
        int rr = i / 41, cc = i - rr * 41;
        out[c * 1681 + i] = p[(size_t)(r0 + rr) * SS + c0 + cc] * inv;
    }
}

// ---------------------------------------------------------------------------
extern "C" void kernel_launch(void* const* d_in, const int* in_sizes, int n_in,
                              void* d_out, int out_size, void* d_ws,
                              size_t ws_size, hipStream_t stream) {
    const float* lms = (const float*)d_in[0];
    const float* fuse = (const float*)d_in[1];
    char* ws = (char*)d_ws;
    float2* Zf = (float2*)ws;                                   // 64 MB: 8 planes
    float2* Wb = (float2*)(ws + ((size_t)64 << 20));            // 32 MB: 4 planes
    float* psf = (float*)ws;                                    // 32 MB, reuses Zf
    ull* am = (ull*)(ws + ((size_t)33 << 20));                  // in dead Zf region
    float* outp = (float*)d_out;

    // 1. blur + alpha blend + pack
    blur_pack_kernel<<<dim3(32, 32, 8), 256, 0, stream>>>(lms, fuse, Zf);
    // 2. forward FFT2 (rows, transpose, rows) -> spectrum in [kx][ky] layout
    fft_rows_kernel<-1><<<8192, 256, 0, stream>>>(Zf, 1.0f);
    transpose_kernel<<<dim3(528, 8), 256, 0, stream>>>(Zf);
    fft_rows_kernel<-1><<<8192, 256, 0, stream>>>(Zf, 1.0f);
    // 3. Wiener pointwise, pack channel pairs
    wiener_kernel<<<16384, 256, 0, stream>>>(Zf, Wb);
    argmax_init_kernel<<<1, 64, 0, stream>>>(am);
    // 4. inverse FFT2 with fused shift/threshold/split on last pass
    fft_rows_kernel<1><<<4096, 256, 0, stream>>>(Wb, 1.0f / 1024.0f);
    transpose_kernel<<<dim3(528, 4), 256, 0, stream>>>(Wb);
    ifft_final_kernel<<<4096, 256, 0, stream>>>(Wb, psf);
    // 5. argmax + crop/normalize
    argmax_kernel<<<dim3(64, 8), 256, 0, stream>>>(psf, am);
    crop_kernel<<<8, 256, 0, stream>>>(psf, am, outp);
}